// Round 3
// baseline (691.347 us; speedup 1.0000x reference)
//
#include <hip/hip_runtime.h>
#include <math.h>

#define N_NODES 100000
#define N_EDGES 3200000
#define F_IN    37
#define H_DIM   16
#define C_DIM   2

#define BUCKET_BITS 9
#define BUCKET_SZ   512                      // nodes per bucket
#define NBUCK       196                      // ceil(100000/512)
#define CHUNK       4096                     // edges per partition block
#define NCHUNK      782                      // ceil(3.2M/4096)
#define EPT         4                        // CHUNK / 1024

// ---------- pass A: degree (global atomics) + bucket histogram (LDS agg) ----------
__global__ __launch_bounds__(1024) void k_deg_hist(
    const int* __restrict__ col, const float* __restrict__ w,
    float* __restrict__ deg, int* __restrict__ bhist)
{
    __shared__ int h[NBUCK];
    int t = threadIdx.x;
    if (t < NBUCK) h[t] = 0;
    __syncthreads();
    int e0 = blockIdx.x * CHUNK;
#pragma unroll
    for (int k = 0; k < EPT; k++) {
        int e = e0 + k * 1024 + t;
        if (e < N_EDGES) {
            int c = col[e];
            atomicAdd(&deg[c], w[e]);
            atomicAdd(&h[c >> BUCKET_BITS], 1);
        }
    }
    __syncthreads();
    if (t < NBUCK && h[t]) atomicAdd(&bhist[t], h[t]);
}

// ---------- dinv = rsqrt(deg + 1) in place ----------
__global__ void k_dinv(float* __restrict__ deg_dinv) {
    int i = blockIdx.x * blockDim.x + threadIdx.x;
    if (i < N_NODES) deg_dinv[i] = rsqrtf(deg_dinv[i] + 1.0f);
}

// ---------- scan 196 bucket counts -> bbase (exclusive) and gcur ----------
__global__ void k_scan196(const int* __restrict__ bhist, int* __restrict__ bbase,
                          int* __restrict__ gcur) {
    __shared__ int s[256];
    int t = threadIdx.x;                     // 256 threads
    int v = (t < NBUCK) ? bhist[t] : 0;
    s[t] = v;
    __syncthreads();
    for (int off = 1; off < 256; off <<= 1) {
        int tmp = (t >= off) ? s[t - off] : 0;
        __syncthreads();
        s[t] += tmp;
        __syncthreads();
    }
    if (t < NBUCK) { int ex = s[t] - v; bbase[t] = ex; gcur[t] = ex; }
    if (t == 0) bbase[NBUCK] = N_EDGES;
}

// ---------- partition: chunk-staged, contiguous bucket runs ----------
// packed edge: (row | col_local<<17, dinv[row]*w)
__global__ __launch_bounds__(1024) void k_part(
    const int* __restrict__ row, const int* __restrict__ col,
    const float* __restrict__ w, const float* __restrict__ dinv,
    int* __restrict__ gcur, int2* __restrict__ ebuf)
{
    __shared__ int  cnt[NBUCK];
    __shared__ int  basel[256];              // inclusive scan
    __shared__ int  gbase[NBUCK];
    __shared__ int2 stage[CHUNK];            // 32 KB

    int t  = threadIdx.x;
    int e0 = blockIdx.x * CHUNK;

    int   bk[EPT], rc[EPT], lofs[EPT];
    float ak[EPT];

    if (t < NBUCK) cnt[t] = 0;
    __syncthreads();
#pragma unroll
    for (int k = 0; k < EPT; k++) {
        int e = e0 + k * 1024 + t;
        if (e < N_EDGES) {
            int r = row[e], c = col[e];
            ak[k] = dinv[r] * w[e];
            bk[k] = c >> BUCKET_BITS;
            rc[k] = r | ((c & (BUCKET_SZ - 1)) << 17);
            lofs[k] = atomicAdd(&cnt[bk[k]], 1);
        } else bk[k] = -1;
    }
    __syncthreads();
    // inclusive scan of cnt over 256 slots
    if (t < 256) basel[t] = (t < NBUCK) ? cnt[t] : 0;
    __syncthreads();
    for (int off = 1; off < 256; off <<= 1) {
        int tmp = 0;
        if (t < 256 && t >= off) tmp = basel[t - off];
        __syncthreads();
        if (t < 256) basel[t] += tmp;
        __syncthreads();
    }
    if (t < NBUCK) gbase[t] = atomicAdd(&gcur[t], cnt[t]);
    __syncthreads();
    int T = basel[NBUCK - 1];
#pragma unroll
    for (int k = 0; k < EPT; k++) {
        if (bk[k] >= 0) {
            int pos = basel[bk[k]] - cnt[bk[k]] + lofs[k];
            stage[pos] = make_int2(rc[k], __float_as_int(ak[k]));
        }
    }
    __syncthreads();
    // contiguous write-out: consecutive s -> consecutive gpos within each run
    for (int s = t; s < T; s += 1024) {
        int lo = 0, hi = NBUCK - 1;
        while (lo < hi) { int mid = (lo + hi) >> 1; if (basel[mid] > s) hi = mid; else lo = mid + 1; }
        int gpos = gbase[lo] + (s - (basel[lo] - cnt[lo]));
        ebuf[gpos] = stage[s];
    }
}

// ---------- h1 = x @ W1 ----------
__global__ void k_xw1(const float* __restrict__ x, const float* __restrict__ W1,
                      float* __restrict__ h1) {
    __shared__ float sW[F_IN * H_DIM];
    for (int t = threadIdx.x; t < F_IN * H_DIM; t += blockDim.x) sW[t] = W1[t];
    __syncthreads();
    int i = blockIdx.x * blockDim.x + threadIdx.x;
    if (i >= N_NODES) return;
    float acc[H_DIM];
#pragma unroll
    for (int j = 0; j < H_DIM; j++) acc[j] = 0.f;
    const float* xi = x + (size_t)i * F_IN;
    for (int k = 0; k < F_IN; k++) {
        float xv = xi[k];
#pragma unroll
        for (int j = 0; j < H_DIM; j++) acc[j] += xv * sW[k * H_DIM + j];
    }
    float* o = h1 + (size_t)i * H_DIM;
#pragma unroll
    for (int j = 0; j < H_DIM; j++) o[j] = acc[j];
}

// ---------- layer 1: bucket LDS accumulate + fused relu/bias + @W2 -> h2 ----------
#define ASTRIDE 18                            // padded node stride (banks spread)
__global__ __launch_bounds__(1024) void k_agg1(
    const int* __restrict__ bbase, const int2* __restrict__ ebuf,
    const float* __restrict__ h1, const float* __restrict__ dinv,
    const float* __restrict__ b1, const float* __restrict__ W2,
    float* __restrict__ h2)
{
    __shared__ float acc[BUCKET_SZ * ASTRIDE];   // 36 KB
    __shared__ float sW2[H_DIM * C_DIM];
    int t = threadIdx.x, b = blockIdx.x;
    int nbase = b << BUCKET_BITS;
    for (int i = t; i < BUCKET_SZ * ASTRIDE; i += 1024) acc[i] = 0.f;
    if (t < H_DIM * C_DIM) sW2[t] = W2[t];
    __syncthreads();

    int s = bbase[b], e = bbase[b + 1];
    const float4* h14 = (const float4*)h1;
    int q = t & 3;
    for (int p = s + (t >> 2); p < e; p += 256) {
        int2 v = ebuf[p];
        float a = __int_as_float(v.y);
        int r  = v.x & 0x1FFFF;
        int cl = v.x >> 17;
        float4 hv = h14[(size_t)r * 4 + q];
        float* ap = &acc[cl * ASTRIDE + (q << 2)];
        atomicAdd(ap + 0, a * hv.x);
        atomicAdd(ap + 1, a * hv.y);
        atomicAdd(ap + 2, a * hv.z);
        atomicAdd(ap + 3, a * hv.w);
    }
    __syncthreads();

    // epilogue: 512 nodes x 4 quad-threads
    for (int i = t; i < BUCKET_SZ * 4; i += 1024) {
        int n = i >> 2, qq = i & 3;
        int c = nbase + n;
        float p0 = 0.f, p1 = 0.f;
        if (c < N_NODES) {
            float dc = dinv[c];
            float sn = dc * dc;
            const float* ap = &acc[n * ASTRIDE + (qq << 2)];
            const float* hc = h1 + (size_t)c * H_DIM + (qq << 2);
            const float* bq = b1 + (qq << 2);
            int j0 = qq << 2;
#pragma unroll
            for (int j = 0; j < 4; j++) {
                float rv = fmaxf(dc * ap[j] + sn * hc[j] + bq[j], 0.f);
                p0 += rv * sW2[(j0 + j) * C_DIM + 0];
                p1 += rv * sW2[(j0 + j) * C_DIM + 1];
            }
        }
        p0 += __shfl_xor(p0, 1); p0 += __shfl_xor(p0, 2);
        p1 += __shfl_xor(p1, 1); p1 += __shfl_xor(p1, 2);
        if (((i & 3) == 0) && c < N_NODES) ((float2*)h2)[c] = make_float2(p0, p1);
    }
}

// ---------- layer 2: bucket LDS accumulate + bias + log_softmax ----------
__global__ __launch_bounds__(512) void k_agg2(
    const int* __restrict__ bbase, const int2* __restrict__ ebuf,
    const float* __restrict__ h2, const float* __restrict__ dinv,
    const float* __restrict__ b2, float* __restrict__ out)
{
    __shared__ float acc[BUCKET_SZ * 2];
    int t = threadIdx.x, b = blockIdx.x;
    int nbase = b << BUCKET_BITS;
    for (int i = t; i < BUCKET_SZ * 2; i += 512) acc[i] = 0.f;
    __syncthreads();
    int s = bbase[b], e = bbase[b + 1];
    const float2* h22 = (const float2*)h2;
    for (int p = s + t; p < e; p += 512) {
        int2 v = ebuf[p];
        float a = __int_as_float(v.y);
        int r  = v.x & 0x1FFFF;
        int cl = v.x >> 17;
        float2 hv = h22[r];
        atomicAdd(&acc[cl * 2 + 0], a * hv.x);
        atomicAdd(&acc[cl * 2 + 1], a * hv.y);
    }
    __syncthreads();
    int c = nbase + t;
    if (c < N_NODES) {
        float dc = dinv[c];
        float sn = dc * dc;
        float2 hc = h22[c];
        float l0 = dc * acc[t * 2 + 0] + sn * hc.x + b2[0];
        float l1 = dc * acc[t * 2 + 1] + sn * hc.y + b2[1];
        float m = fmaxf(l0, l1);
        float lse = m + logf(expf(l0 - m) + expf(l1 - m));
        ((float2*)out)[c] = make_float2(l0 - lse, l1 - lse);
    }
}

extern "C" void kernel_launch(void* const* d_in, const int* in_sizes, int n_in,
                              void* d_out, int out_size, void* d_ws, size_t ws_size,
                              hipStream_t stream) {
    const float* x  = (const float*)d_in[0];
    const int*   ei = (const int*)d_in[1];     // [2, E]: row then col
    const float* w  = (const float*)d_in[2];
    const float* W1 = (const float*)d_in[3];
    const float* b1 = (const float*)d_in[4];
    const float* W2 = (const float*)d_in[5];
    const float* b2 = (const float*)d_in[6];
    float* out = (float*)d_out;

    const int* row = ei;
    const int* col = ei + N_EDGES;

    // workspace layout (16B-aligned)
    char* ws = (char*)d_ws;
    float* deg_dinv = (float*)(ws + 0);          //   400,000 B (deg -> dinv in place)
    int*   bhist    = (int*)(ws + 400000);       //       800 B
    int*   bbase    = (int*)(ws + 400800);       //       800 B (NBUCK+1)
    int*   gcur     = (int*)(ws + 401600);       //       800 B
    int2*  ebuf     = (int2*)(ws + 409600);      //25,600,000 B
    float* h1       = (float*)(ws + 26009600);   // 6,400,000 B
    float* h2       = (float*)(ws + 32409600);   //   800,000 B
    // end: 33,209,600 B

    hipMemsetAsync(ws, 0, 400800, stream);       // deg + bhist

    k_deg_hist<<<NCHUNK, 1024, 0, stream>>>(col, w, deg_dinv, bhist);
    k_dinv    <<<(N_NODES + 255) / 256, 256, 0, stream>>>(deg_dinv);
    k_scan196 <<<1, 256, 0, stream>>>(bhist, bbase, gcur);
    k_part    <<<NCHUNK, 1024, 0, stream>>>(row, col, w, deg_dinv, gcur, ebuf);
    k_xw1     <<<(N_NODES + 255) / 256, 256, 0, stream>>>(x, W1, h1);
    k_agg1    <<<NBUCK, 1024, 0, stream>>>(bbase, ebuf, h1, deg_dinv, b1, W2, h2);
    k_agg2    <<<NBUCK, 512, 0, stream>>>(bbase, ebuf, h2, deg_dinv, b2, out);
}

// Round 4
// 551.360 us; speedup vs baseline: 1.2539x; 1.2539x over previous
//
#include <hip/hip_runtime.h>
#include <math.h>

#define N_NODES 100000
#define N_EDGES 3200000
#define F_IN    37
#define H_DIM   16
#define C_DIM   2

#define BUCKET_BITS 7
#define BUCKET_SZ   128
#define NBUCK       782          // ceil(100000/128)
#define CAP         4608         // bucket capacity: mean 4096 + 8 sigma
#define CHUNK       4096
#define NCHUNK      782          // ceil(3.2M/4096)
#define EPT         4
#define ASTRIDE     17           // padded per-node LDS stride (floats)

// ---------- init bucket cursors ----------
__global__ void k_init(int* __restrict__ gcur) {
    int i = blockIdx.x * blockDim.x + threadIdx.x;
    if (i < NBUCK) gcur[i] = i * CAP;
}

// ---------- partition edges into destination buckets (no dinv needed) ----------
// packed: (row | col_local<<17, w)
__global__ __launch_bounds__(1024) void k_part(
    const int* __restrict__ row, const int* __restrict__ col,
    const float* __restrict__ w, int* __restrict__ gcur, int2* __restrict__ ebuf)
{
    __shared__ int cnt[NBUCK];
    __shared__ int gbase[NBUCK];
    int t = threadIdx.x;
    int e0 = blockIdx.x * CHUNK;
    int bk[EPT], rc[EPT], lofs[EPT];
    float wv[EPT];

    if (t < NBUCK) cnt[t] = 0;
    __syncthreads();
#pragma unroll
    for (int k = 0; k < EPT; k++) {
        int e = e0 + k * 1024 + t;
        if (e < N_EDGES) {
            int r = row[e], c = col[e];
            wv[k] = w[e];
            bk[k] = c >> BUCKET_BITS;
            rc[k] = r | ((c & (BUCKET_SZ - 1)) << 17);
            lofs[k] = atomicAdd(&cnt[bk[k]], 1);
        } else bk[k] = -1;
    }
    __syncthreads();
    if (t < NBUCK) gbase[t] = atomicAdd(&gcur[t], cnt[t]);
    __syncthreads();
#pragma unroll
    for (int k = 0; k < EPT; k++) {
        if (bk[k] >= 0)
            ebuf[gbase[bk[k]] + lofs[k]] = make_int2(rc[k], __float_as_int(wv[k]));
    }
}

// ---------- per-bucket degree from partitioned edges -> dinv ----------
__global__ __launch_bounds__(256) void k_deg_seg(
    const int* __restrict__ gcur, const int2* __restrict__ ebuf,
    float* __restrict__ dinv)
{
    __shared__ float dsum[BUCKET_SZ];
    int t = threadIdx.x, b = blockIdx.x;
    if (t < BUCKET_SZ) dsum[t] = 0.f;
    __syncthreads();
    int s = b * CAP, e = gcur[b];
    for (int p = s + t; p < e; p += 256) {
        int2 v = ebuf[p];
        atomicAdd(&dsum[v.x >> 17], __int_as_float(v.y));
    }
    __syncthreads();
    int c = (b << BUCKET_BITS) + t;
    if (t < BUCKET_SZ && c < N_NODES) dinv[c] = rsqrtf(dsum[t] + 1.0f);
}

// ---------- h1s = dinv * (x @ W1), x staged via LDS ----------
__global__ __launch_bounds__(256) void k_xw1(
    const float* __restrict__ x, const float* __restrict__ W1,
    const float* __restrict__ dinv, float* __restrict__ h1s)
{
    __shared__ float xs[256 * F_IN];          // 37.9 KB
    __shared__ float sW[F_IN * H_DIM];
    int t = threadIdx.x;
    int nb = blockIdx.x * 256;
    for (int idx = t; idx < F_IN * H_DIM; idx += 256) sW[idx] = W1[idx];
    int g0 = nb * F_IN;
    for (int idx = t; idx < 256 * F_IN; idx += 256) {
        int gi = g0 + idx;
        if (gi < N_NODES * F_IN) xs[idx] = x[gi];
    }
    __syncthreads();
    int i = nb + t;
    if (i >= N_NODES) return;
    float acc[H_DIM];
#pragma unroll
    for (int j = 0; j < H_DIM; j++) acc[j] = 0.f;
    const float* xi = &xs[t * F_IN];
    for (int k = 0; k < F_IN; k++) {
        float xv = xi[k];
#pragma unroll
        for (int j = 0; j < H_DIM; j++) acc[j] += xv * sW[k * H_DIM + j];
    }
    float di = dinv[i];
    float4* o = (float4*)(h1s + (size_t)i * H_DIM);
#pragma unroll
    for (int j = 0; j < 4; j++)
        o[j] = make_float4(di * acc[j * 4 + 0], di * acc[j * 4 + 1],
                           di * acc[j * 4 + 2], di * acc[j * 4 + 3]);
}

// ---------- layer 1: bucket LDS accumulate + fused relu/bias + @W2 -> h2s ----------
__global__ __launch_bounds__(512) void k_agg1(
    const int* __restrict__ gcur, const int2* __restrict__ ebuf,
    const float* __restrict__ h1s, const float* __restrict__ dinv,
    const float* __restrict__ b1, const float* __restrict__ W2,
    float* __restrict__ h2s)
{
    __shared__ float acc[BUCKET_SZ * ASTRIDE];   // 8.7 KB
    __shared__ float sW2[H_DIM * C_DIM];
    __shared__ float sb1[H_DIM];
    int t = threadIdx.x, b = blockIdx.x;
    int nbase = b << BUCKET_BITS;
    for (int i = t; i < BUCKET_SZ * ASTRIDE; i += 512) acc[i] = 0.f;
    if (t < H_DIM * C_DIM) sW2[t] = W2[t];
    if (t >= 64 && t < 64 + H_DIM) sb1[t - 64] = b1[t - 64];
    __syncthreads();

    int s = b * CAP, e = gcur[b];
    const float4* h14 = (const float4*)h1s;
    int q = t & 3;
    int p = s + (t >> 2);
    bool have = p < e;
    int2 v;
    if (have) v = ebuf[p];
    while (have) {
        int2 cur = v;
        int pn = p + 128;
        have = pn < e;
        if (have) v = ebuf[pn];
        p = pn;
        float a = __int_as_float(cur.y);
        int r  = cur.x & 0x1FFFF;
        int cl = cur.x >> 17;
        float4 hv = h14[(size_t)r * 4 + q];
        float* ap = &acc[cl * ASTRIDE + (q << 2)];
        atomicAdd(ap + 0, a * hv.x);
        atomicAdd(ap + 1, a * hv.y);
        atomicAdd(ap + 2, a * hv.z);
        atomicAdd(ap + 3, a * hv.w);
    }
    __syncthreads();

    // epilogue: 128 nodes x 4 quad-lanes = 512 threads
    int n = t >> 2;
    int c = nbase + n;
    float p0 = 0.f, p1 = 0.f;
    float dc = 0.f;
    if (c < N_NODES) {
        dc = dinv[c];
        const float* ap = &acc[n * ASTRIDE + (q << 2)];
        float4 hc = h14[(size_t)c * 4 + q];
        int j0 = q << 2;
        float hcv[4] = {hc.x, hc.y, hc.z, hc.w};
#pragma unroll
        for (int j = 0; j < 4; j++) {
            float rv = fmaxf(dc * (ap[j] + hcv[j]) + sb1[j0 + j], 0.f);
            p0 += rv * sW2[(j0 + j) * C_DIM + 0];
            p1 += rv * sW2[(j0 + j) * C_DIM + 1];
        }
    }
    p0 += __shfl_xor(p0, 1); p0 += __shfl_xor(p0, 2);
    p1 += __shfl_xor(p1, 1); p1 += __shfl_xor(p1, 2);
    if (q == 0 && c < N_NODES) ((float2*)h2s)[c] = make_float2(dc * p0, dc * p1);
}

// ---------- layer 2: bucket LDS accumulate + bias + log_softmax ----------
__global__ __launch_bounds__(256) void k_agg2(
    const int* __restrict__ gcur, const int2* __restrict__ ebuf,
    const float* __restrict__ h2s, const float* __restrict__ dinv,
    const float* __restrict__ b2, float* __restrict__ out)
{
    __shared__ float acc[BUCKET_SZ * 2];
    int t = threadIdx.x, b = blockIdx.x;
    int nbase = b << BUCKET_BITS;
    if (t < BUCKET_SZ * 2) acc[t] = 0.f;
    __syncthreads();
    int s = b * CAP, e = gcur[b];
    const float2* h22 = (const float2*)h2s;
    int p = s + t;
    bool have = p < e;
    int2 v;
    if (have) v = ebuf[p];
    while (have) {
        int2 cur = v;
        int pn = p + 256;
        have = pn < e;
        if (have) v = ebuf[pn];
        p = pn;
        float a = __int_as_float(cur.y);
        int r  = cur.x & 0x1FFFF;
        int cl = cur.x >> 17;
        float2 hv = h22[r];
        atomicAdd(&acc[cl * 2 + 0], a * hv.x);
        atomicAdd(&acc[cl * 2 + 1], a * hv.y);
    }
    __syncthreads();
    int c = nbase + t;
    if (t < BUCKET_SZ && c < N_NODES) {
        float dc = dinv[c];
        float2 hc = h22[c];
        float l0 = dc * (acc[t * 2 + 0] + hc.x) + b2[0];
        float l1 = dc * (acc[t * 2 + 1] + hc.y) + b2[1];
        float m = fmaxf(l0, l1);
        float lse = m + logf(expf(l0 - m) + expf(l1 - m));
        ((float2*)out)[c] = make_float2(l0 - lse, l1 - lse);
    }
}

extern "C" void kernel_launch(void* const* d_in, const int* in_sizes, int n_in,
                              void* d_out, int out_size, void* d_ws, size_t ws_size,
                              hipStream_t stream) {
    const float* x  = (const float*)d_in[0];
    const int*   ei = (const int*)d_in[1];     // [2, E]: row then col
    const float* w  = (const float*)d_in[2];
    const float* W1 = (const float*)d_in[3];
    const float* b1 = (const float*)d_in[4];
    const float* W2 = (const float*)d_in[5];
    const float* b2 = (const float*)d_in[6];
    float* out = (float*)d_out;

    const int* row = ei;
    const int* col = ei + N_EDGES;

    // workspace layout
    char* ws = (char*)d_ws;
    int*   gcur = (int*)(ws + 0);                //     3,200 B (782 ints, padded)
    int2*  ebuf = (int2*)(ws + 3200);            //28,827,648 B (782*4608*8)
    float* dinv = (float*)(ws + 28830848);       //   400,000 B
    float* h1s  = (float*)(ws + 29230848);       // 6,400,000 B
    float* h2s  = (float*)(ws + 35630848);       //   800,000 B
    // end: 36,430,848 B

    k_init   <<<4, 256, 0, stream>>>(gcur);
    k_part   <<<NCHUNK, 1024, 0, stream>>>(row, col, w, gcur, ebuf);
    k_deg_seg<<<NBUCK, 256, 0, stream>>>(gcur, ebuf, dinv);
    k_xw1    <<<(N_NODES + 255) / 256, 256, 0, stream>>>(x, W1, dinv, h1s);
    k_agg1   <<<NBUCK, 512, 0, stream>>>(gcur, ebuf, h1s, dinv, b1, W2, h2s);
    k_agg2   <<<NBUCK, 256, 0, stream>>>(gcur, ebuf, h2s, dinv, b2, out);
}